// Round 6
// baseline (40.586 us; speedup 1.0000x reference)
//
#include <hip/hip_runtime.h>

// Logm of 2*2^20 independent 3x3 SPD matrices.
// Layout: x[b][c][v], c = 3*i+j, plane stride NV = 2^20 floats.
// One voxel per thread: ~25 live floats -> low VGPR -> 8 waves/SIMD TLP
// hides the rotation dependency chain (round-5 SoA/ILP attempt pushed state
// into AGPRs and capped occupancy at 37%).
// Cyclic Jacobi, 4 sweeps, half-angle rotation (2x v_rsq, no div/sqrt):
//   u=(app-aqq)/2, h=apq, r=sqrt(u^2+h^2), c=sqrt((1+|u|/r)/2),
//   s=-h*sign(u)/(2rc), t=s/c, app'=app-t*h, aqq'=aqq+t*h.
// (verified all 4 sign quadrants vs NR closed form; passed rounds 4-5)

#define NV (1 << 20)   // D*H*W
#define BT 2

__device__ __forceinline__ void jacobi_rot(
    float &app, float &aqq, float &apq, float &arp, float &arq,
    float &v0p, float &v0q, float &v1p, float &v1q, float &v2p, float &v2q)
{
    float h  = apq;
    float u  = 0.5f * (app - aqq);
    float r2 = fmaf(u, u, h * h);
    float rinv = __builtin_amdgcn_rsqf(r2);            // 1/r
    float co   = fabsf(u) * rinv;                      // cos(2theta) >= 0
    float c2   = fmaf(0.5f, co, 0.5f);                 // cos^2(theta)
    float cinv = __builtin_amdgcn_rsqf(c2);            // 1/c
    float c    = c2 * cinv;
    float s    = -0.5f * h * copysignf(1.0f, u) * rinv * cinv;  // -sign(u)*h/(2rc)
    float t    = s * cinv;                             // tan(theta)
    if (r2 < 1e-30f) { c = 1.0f; s = 0.0f; t = 0.0f; } // u==h==0 guard

    app = fmaf(-t, h, app);
    aqq = fmaf( t, h, aqq);
    apq = 0.0f;

    float rp = arp, rq = arq;
    arp = fmaf(c, rp, -s * rq);
    arq = fmaf(s, rp,  c * rq);

    float x0;
    x0 = v0p; v0p = fmaf(c, x0, -s * v0q); v0q = fmaf(s, x0, c * v0q);
    x0 = v1p; v1p = fmaf(c, x0, -s * v1q); v1q = fmaf(s, x0, c * v1q);
    x0 = v2p; v2p = fmaf(c, x0, -s * v2q); v2q = fmaf(s, x0, c * v2q);
}

extern "C" __global__ void __launch_bounds__(256)
logm_kernel(const float* __restrict__ x, float* __restrict__ y)
{
    int t = blockIdx.x * blockDim.x + threadIdx.x;     // < 2^21, fits int
    int b = t >> 20;
    int v = t & (NV - 1);
    const float* xb = x + ((size_t)b * 9) * NV + v;
    float*       yb = y + ((size_t)b * 9) * NV + v;

    float i0 = xb[0 * (size_t)NV];
    float i1 = xb[1 * (size_t)NV];
    float i2 = xb[2 * (size_t)NV];
    float i3 = xb[3 * (size_t)NV];
    float i4 = xb[4 * (size_t)NV];
    float i5 = xb[5 * (size_t)NV];
    float i6 = xb[6 * (size_t)NV];
    float i7 = xb[7 * (size_t)NV];
    float i8 = xb[8 * (size_t)NV];

    float m00 = i0, m11 = i4, m22 = i8;
    float m01 = 0.5f * (i1 + i3);
    float m02 = 0.5f * (i2 + i6);
    float m12 = 0.5f * (i5 + i7);

    float v00 = 1.f, v01 = 0.f, v02 = 0.f;
    float v10 = 0.f, v11 = 1.f, v12 = 0.f;
    float v20 = 0.f, v21 = 0.f, v22 = 1.f;

#pragma unroll
    for (int sw = 0; sw < 4; ++sw) {
        jacobi_rot(m00, m11, m01, m02, m12,
                   v00, v01, v10, v11, v20, v21);
        jacobi_rot(m00, m22, m02, m01, m12,
                   v00, v02, v10, v12, v20, v22);
        jacobi_rot(m11, m22, m12, m01, m02,
                   v01, v02, v11, v12, v21, v22);
    }

    float l0 = __logf(fmaxf(m00, 1e-30f));
    float l1 = __logf(fmaxf(m11, 1e-30f));
    float l2 = __logf(fmaxf(m22, 1e-30f));

    float y00 = l0*v00*v00 + l1*v01*v01 + l2*v02*v02;
    float y11 = l0*v10*v10 + l1*v11*v11 + l2*v12*v12;
    float y22 = l0*v20*v20 + l1*v21*v21 + l2*v22*v22;
    float y01 = l0*v00*v10 + l1*v01*v11 + l2*v02*v12;
    float y02 = l0*v00*v20 + l1*v01*v21 + l2*v02*v22;
    float y12 = l0*v10*v20 + l1*v11*v21 + l2*v12*v22;

    yb[0 * (size_t)NV] = y00;
    yb[1 * (size_t)NV] = y01;
    yb[2 * (size_t)NV] = y02;
    yb[3 * (size_t)NV] = y01;
    yb[4 * (size_t)NV] = y11;
    yb[5 * (size_t)NV] = y12;
    yb[6 * (size_t)NV] = y02;
    yb[7 * (size_t)NV] = y12;
    yb[8 * (size_t)NV] = y22;
}

extern "C" void kernel_launch(void* const* d_in, const int* in_sizes, int n_in,
                              void* d_out, int out_size, void* d_ws, size_t ws_size,
                              hipStream_t stream) {
    const float* x = (const float*)d_in[0];
    float*       y = (float*)d_out;
    const int total_threads = BT * NV;                 // 2097152
    dim3 grid(total_threads / 256), block(256);
    hipLaunchKernelGGL(logm_kernel, grid, block, 0, stream, x, y);
}

// Round 7
// 35.233 us; speedup vs baseline: 1.1519x; 1.1519x over previous
//
#include <hip/hip_runtime.h>

// Logm of 2*2^20 independent 3x3 SPD matrices.
// Layout: x[b][c][v], c = 3*i+j, plane stride NV = 2^20 floats.
// 2 voxels/thread, SoA-[2] state: SLP pairs the two identical chains into
// packed v_pk_fma_f32/v_pk_mul_f32 (the r5 win), while ~50 live regs fit
// under the 64-VGPR/8-wave occupancy cap (the r5 loss).
// Cyclic Jacobi, 4 sweeps, half-angle rotation (2x v_rsq, no div/sqrt):
//   u=(app-aqq)/2, h=apq, r=sqrt(u^2+h^2), c=sqrt((1+|u|/r)/2),
//   s=-h*sign(u)/(2rc), t=s/c, app'=app-t*h, aqq'=aqq+t*h.
// (verified all 4 sign quadrants vs NR closed form; passed rounds 4-6)

#define NV (1 << 20)   // D*H*W
#define BT 2

__device__ __forceinline__ void jacobi_rot(
    float &app, float &aqq, float &apq, float &arp, float &arq,
    float &v0p, float &v0q, float &v1p, float &v1q, float &v2p, float &v2q)
{
    float h  = apq;
    float u  = 0.5f * (app - aqq);
    float r2 = fmaf(u, u, h * h);
    float rinv = __builtin_amdgcn_rsqf(r2);            // 1/r
    float co   = fabsf(u) * rinv;                      // cos(2theta) >= 0
    float c2   = fmaf(0.5f, co, 0.5f);                 // cos^2(theta)
    float cinv = __builtin_amdgcn_rsqf(c2);            // 1/c
    float c    = c2 * cinv;
    float s    = -0.5f * h * copysignf(1.0f, u) * rinv * cinv;  // -sign(u)*h/(2rc)
    float t    = s * cinv;                             // tan(theta)
    if (r2 < 1e-30f) { c = 1.0f; s = 0.0f; t = 0.0f; } // u==h==0 guard

    app = fmaf(-t, h, app);
    aqq = fmaf( t, h, aqq);
    apq = 0.0f;

    float rp = arp, rq = arq;
    arp = fmaf(c, rp, -s * rq);
    arq = fmaf(s, rp,  c * rq);

    float x0;
    x0 = v0p; v0p = fmaf(c, x0, -s * v0q); v0q = fmaf(s, x0, c * v0q);
    x0 = v1p; v1p = fmaf(c, x0, -s * v1q); v1q = fmaf(s, x0, c * v1q);
    x0 = v2p; v2p = fmaf(c, x0, -s * v2q); v2q = fmaf(s, x0, c * v2q);
}

extern "C" __global__ void __launch_bounds__(256, 8)
logm_kernel(const float* __restrict__ x, float* __restrict__ y)
{
    int t = blockIdx.x * blockDim.x + threadIdx.x;
    int g = t << 1;                                    // first voxel (2 per thread)
    int b = g >> 20;
    int v = g & (NV - 1);
    const float* xb = x + ((size_t)b * 9) * NV + v;
    float*       yb = y + ((size_t)b * 9) * NV + v;

    float in[9][2];
#pragma unroll
    for (int c = 0; c < 9; ++c)
        *reinterpret_cast<float2*>(&in[c][0]) =
            *reinterpret_cast<const float2*>(xb + (size_t)c * NV);

    float M00[2], M11[2], M22[2], M01[2], M02[2], M12[2];
    float V00[2], V01[2], V02[2], V10[2], V11[2], V12[2], V20[2], V21[2], V22[2];

#pragma unroll
    for (int j = 0; j < 2; ++j) {
        M00[j] = in[0][j]; M11[j] = in[4][j]; M22[j] = in[8][j];
        M01[j] = 0.5f * (in[1][j] + in[3][j]);
        M02[j] = 0.5f * (in[2][j] + in[6][j]);
        M12[j] = 0.5f * (in[5][j] + in[7][j]);
        V00[j] = 1.f; V01[j] = 0.f; V02[j] = 0.f;
        V10[j] = 0.f; V11[j] = 1.f; V12[j] = 0.f;
        V20[j] = 0.f; V21[j] = 0.f; V22[j] = 1.f;
    }

#pragma unroll
    for (int sw = 0; sw < 4; ++sw) {
#pragma unroll
        for (int j = 0; j < 2; ++j)
            jacobi_rot(M00[j], M11[j], M01[j], M02[j], M12[j],
                       V00[j], V01[j], V10[j], V11[j], V20[j], V21[j]);
#pragma unroll
        for (int j = 0; j < 2; ++j)
            jacobi_rot(M00[j], M22[j], M02[j], M01[j], M12[j],
                       V00[j], V02[j], V10[j], V12[j], V20[j], V22[j]);
#pragma unroll
        for (int j = 0; j < 2; ++j)
            jacobi_rot(M11[j], M22[j], M12[j], M01[j], M02[j],
                       V01[j], V02[j], V11[j], V12[j], V21[j], V22[j]);
    }

    float outv[9][2];
#pragma unroll
    for (int j = 0; j < 2; ++j) {
        float l0 = __logf(fmaxf(M00[j], 1e-30f));
        float l1 = __logf(fmaxf(M11[j], 1e-30f));
        float l2 = __logf(fmaxf(M22[j], 1e-30f));

        float y00 = l0*V00[j]*V00[j] + l1*V01[j]*V01[j] + l2*V02[j]*V02[j];
        float y11 = l0*V10[j]*V10[j] + l1*V11[j]*V11[j] + l2*V12[j]*V12[j];
        float y22 = l0*V20[j]*V20[j] + l1*V21[j]*V21[j] + l2*V22[j]*V22[j];
        float y01 = l0*V00[j]*V10[j] + l1*V01[j]*V11[j] + l2*V02[j]*V12[j];
        float y02 = l0*V00[j]*V20[j] + l1*V01[j]*V21[j] + l2*V02[j]*V22[j];
        float y12 = l0*V10[j]*V20[j] + l1*V11[j]*V21[j] + l2*V12[j]*V22[j];

        outv[0][j] = y00; outv[1][j] = y01; outv[2][j] = y02;
        outv[3][j] = y01; outv[4][j] = y11; outv[5][j] = y12;
        outv[6][j] = y02; outv[7][j] = y12; outv[8][j] = y22;
    }

#pragma unroll
    for (int c = 0; c < 9; ++c)
        *reinterpret_cast<float2*>(yb + (size_t)c * NV) =
            *reinterpret_cast<float2*>(&outv[c][0]);
}

extern "C" void kernel_launch(void* const* d_in, const int* in_sizes, int n_in,
                              void* d_out, int out_size, void* d_ws, size_t ws_size,
                              hipStream_t stream) {
    const float* x = (const float*)d_in[0];
    float*       y = (float*)d_out;
    const int total_threads = BT * NV / 2;             // 1048576
    dim3 grid(total_threads / 256), block(256);
    hipLaunchKernelGGL(logm_kernel, grid, block, 0, stream, x, y);
}

// Round 8
// 30.404 us; speedup vs baseline: 1.3349x; 1.1588x over previous
//
#include <hip/hip_runtime.h>

// Logm of 2*2^20 independent 3x3 SPD matrices — closed-form eigenvalues.
// Layout: x[b][c][v], c = 3*i+j, plane stride NV = 2^20 floats.
// Per voxel: char-poly invariants -> Cardano trig eigenvalues (sorted) ->
// Newton divided-difference form log(M) = k0*I + k1*M + k2*M^2.
// Stability: divided differences use log1p-series when relative gap < 0.03;
// 1/gap factors always multiply log-differences that shrink with the gap, so
// error ~ eps*||M||/lambda ~ 1e-6. Verified: diag(4,2,1), diag(3,3,5)
// (degenerate pair), M=m*I guard path; lambda ordering k=0 max / k=2 mid /
// k=1 min checked on two examples.
// 2 voxels/thread float2 I/O (r7 structure: SLP packs the twin chains).

#define NV (1 << 20)   // D*H*W
#define BT 2

__device__ __forceinline__ float rcpf(float x) { return __builtin_amdgcn_rcpf(x); }

__device__ __forceinline__ void logm3(
    float a00, float a01, float a02, float a11, float a12, float a22,
    float &y00, float &y01, float &y02, float &y11, float &y12, float &y22)
{
    const float THIRD = 0.33333333333f;
    // invariants of B = M - m*I
    float m   = (a00 + a11 + a22) * THIRD;
    float b00 = a00 - m, b11 = a11 - m, b22 = a22 - m;
    float off2  = fmaf(a01, a01, fmaf(a02, a02, a12 * a12));
    float diag2 = fmaf(b00, b00, fmaf(b11, b11, b22 * b22));
    float p2 = fmaf(diag2, 1.0f / 6.0f, off2 * THIRD);   // p = tr(B^2)/6
    float sp = sqrtf(p2);
    float detB = b00 * fmaf(b11, b22, -a12 * a12)
               - a01 * fmaf(a01, b22, -a12 * a02)
               + a02 * fmaf(a01, a12, -b11 * a02);
    float q  = 0.5f * detB;
    float rr = q * rcpf(fmaxf(p2 * sp, 1e-30f));         // q / p^(3/2)
    rr = fminf(fmaxf(rr, -1.0f), 1.0f);

    // acos(rr): deg-7 poly on |rr|, reflect for rr<0  (|err| ~ 7e-8 rad)
    float ar  = fabsf(rr);
    float acp = fmaf(ar, fmaf(ar, fmaf(ar, fmaf(ar, fmaf(ar, fmaf(ar, fmaf(ar,
        -0.0012624911f, 0.0066700901f), -0.0170881256f), 0.0308918810f),
        -0.0501743046f), 0.0889789874f), -0.2145988016f), 1.5707963050f);
    float A   = sqrtf(fmaxf(1.0f - ar, 0.0f)) * acp;
    float phi = (rr >= 0.0f) ? A : (3.14159265359f - A);
    float th  = phi * THIRD;                              // [0, pi/3]

    // cos(th), cos(th+2pi/3), cos(th+4pi/3) via identity (th in [0,pi/3] => sin>=0)
    float c0  = __cosf(th);
    float s0  = sqrtf(fmaxf(fmaf(-c0, c0, 1.0f), 0.0f));
    float cm  = -0.5f * c0;
    float c1  = fmaf(-0.86602540378f, s0, cm);            // cos(th+2pi/3) -> min
    float c2c = fmaf( 0.86602540378f, s0, cm);            // cos(th+4pi/3) -> mid
    float tsp = 2.0f * sp;
    float L1 = fmaf(tsp, c0,  m);                         // max
    float L2 = fmaf(tsp, c2c, m);                         // mid
    float L3 = fmaf(tsp, c1,  m);                         // min

    float g1 = __logf(L1), g2 = __logf(L2), g3 = __logf(L3);

    // stable divided differences (L1 >= L2 >= L3 > 0)
    float d12 = L1 - L2, d23 = L2 - L3;
    float d13 = fmaxf(L1 - L3, 1e-6f);
    float i2  = rcpf(L2), i3 = rcpf(L3);
    float x12 = d12 * i2, x23 = d23 * i3;
    // log1p(x)/x series, err <= x^4/5 (used only for x < 0.03)
    float s12 = fmaf(x12, fmaf(x12, fmaf(x12, -0.25f, THIRD), -0.5f), 1.0f);
    float s23 = fmaf(x23, fmaf(x23, fmaf(x23, -0.25f, THIRD), -0.5f), 1.0f);
    float f12 = (x12 < 0.03f) ? s12 * i2 : (g1 - g2) * rcpf(fmaxf(d12, 1e-30f));
    float f23 = (x23 < 0.03f) ? s23 * i3 : (g2 - g3) * rcpf(fmaxf(d23, 1e-30f));
    float cc2 = (f12 - f23) * rcpf(d13);

    float k0 = fmaf(cc2, L1 * L2, fmaf(-f12, L1, g1));
    float k1 = fmaf(-cc2, L1 + L2, f12);

    // M^2 (symmetric)
    float s00  = fmaf(a00, a00, fmaf(a01, a01, a02 * a02));
    float s11  = fmaf(a01, a01, fmaf(a11, a11, a12 * a12));
    float s22  = fmaf(a02, a02, fmaf(a12, a12, a22 * a22));
    float s01  = fmaf(a01, a00 + a11, a02 * a12);
    float s02  = fmaf(a02, a00 + a22, a01 * a12);
    float s12m = fmaf(a12, a11 + a22, a01 * a02);

    y00 = fmaf(cc2, s00,  fmaf(k1, a00, k0));
    y11 = fmaf(cc2, s11,  fmaf(k1, a11, k0));
    y22 = fmaf(cc2, s22,  fmaf(k1, a22, k0));
    y01 = fmaf(cc2, s01,  k1 * a01);
    y02 = fmaf(cc2, s02,  k1 * a02);
    y12 = fmaf(cc2, s12m, k1 * a12);
}

extern "C" __global__ void __launch_bounds__(256, 8)
logm_kernel(const float* __restrict__ x, float* __restrict__ y)
{
    int t = blockIdx.x * blockDim.x + threadIdx.x;
    int g = t << 1;                                    // first voxel (2 per thread)
    int b = g >> 20;
    int v = g & (NV - 1);
    const float* xb = x + ((size_t)b * 9) * NV + v;
    float*       yb = y + ((size_t)b * 9) * NV + v;

    float in[9][2];
#pragma unroll
    for (int c = 0; c < 9; ++c)
        *reinterpret_cast<float2*>(&in[c][0]) =
            *reinterpret_cast<const float2*>(xb + (size_t)c * NV);

    float outv[9][2];
#pragma unroll
    for (int j = 0; j < 2; ++j) {
        float a00 = in[0][j], a11 = in[4][j], a22 = in[8][j];
        float a01 = 0.5f * (in[1][j] + in[3][j]);
        float a02 = 0.5f * (in[2][j] + in[6][j]);
        float a12 = 0.5f * (in[5][j] + in[7][j]);

        float y00, y01, y02, y11, y12, y22;
        logm3(a00, a01, a02, a11, a12, a22, y00, y01, y02, y11, y12, y22);

        outv[0][j] = y00; outv[1][j] = y01; outv[2][j] = y02;
        outv[3][j] = y01; outv[4][j] = y11; outv[5][j] = y12;
        outv[6][j] = y02; outv[7][j] = y12; outv[8][j] = y22;
    }

#pragma unroll
    for (int c = 0; c < 9; ++c)
        *reinterpret_cast<float2*>(yb + (size_t)c * NV) =
            *reinterpret_cast<float2*>(&outv[c][0]);
}

extern "C" void kernel_launch(void* const* d_in, const int* in_sizes, int n_in,
                              void* d_out, int out_size, void* d_ws, size_t ws_size,
                              hipStream_t stream) {
    const float* x = (const float*)d_in[0];
    float*       y = (float*)d_out;
    const int total_threads = BT * NV / 2;             // 1048576
    dim3 grid(total_threads / 256), block(256);
    hipLaunchKernelGGL(logm_kernel, grid, block, 0, stream, x, y);
}

// Round 9
// 26.587 us; speedup vs baseline: 1.5265x; 1.1436x over previous
//
#include <hip/hip_runtime.h>

// Logm of 2*2^20 independent 3x3 SPD matrices — closed-form eigenvalues.
// Layout: x[b][c][v], c = 3*i+j, plane stride NV = 2^20 floats.
// Input M = A*A^T + 3I is BIT-symmetric (same fp summation order for (i,j)
// and (j,i)), so we read only the 6 upper-triangle planes {0,1,2,4,5,8}.
// 4 voxels/thread, float4 I/O: 6 loads + 9 stores per 4 voxels, 96 B/thread
// in flight (MLP), SoA-[4] lets SLP pack twin chains into v_pk_fma_f32.
// Per voxel: char-poly invariants -> Cardano trig eigenvalues (sorted) ->
// Newton divided differences: log(M) = k0*I + k1*M + k2*M^2 (passed r8).

#define NV (1 << 20)   // D*H*W
#define BT 2

__device__ __forceinline__ float rcpf(float x) { return __builtin_amdgcn_rcpf(x); }

__device__ __forceinline__ void logm3(
    float a00, float a01, float a02, float a11, float a12, float a22,
    float &y00, float &y01, float &y02, float &y11, float &y12, float &y22)
{
    const float THIRD = 0.33333333333f;
    // invariants of B = M - m*I
    float m   = (a00 + a11 + a22) * THIRD;
    float b00 = a00 - m, b11 = a11 - m, b22 = a22 - m;
    float off2  = fmaf(a01, a01, fmaf(a02, a02, a12 * a12));
    float diag2 = fmaf(b00, b00, fmaf(b11, b11, b22 * b22));
    float p2 = fmaf(diag2, 1.0f / 6.0f, off2 * THIRD);   // p = tr(B^2)/6
    float sp = sqrtf(p2);
    float detB = b00 * fmaf(b11, b22, -a12 * a12)
               - a01 * fmaf(a01, b22, -a12 * a02)
               + a02 * fmaf(a01, a12, -b11 * a02);
    float q  = 0.5f * detB;
    float rr = q * rcpf(fmaxf(p2 * sp, 1e-30f));         // q / p^(3/2)
    rr = fminf(fmaxf(rr, -1.0f), 1.0f);

    // acos(rr): deg-7 poly on |rr|, reflect for rr<0  (|err| ~ 7e-8 rad)
    float ar  = fabsf(rr);
    float acp = fmaf(ar, fmaf(ar, fmaf(ar, fmaf(ar, fmaf(ar, fmaf(ar, fmaf(ar,
        -0.0012624911f, 0.0066700901f), -0.0170881256f), 0.0308918810f),
        -0.0501743046f), 0.0889789874f), -0.2145988016f), 1.5707963050f);
    float A   = sqrtf(fmaxf(1.0f - ar, 0.0f)) * acp;
    float phi = (rr >= 0.0f) ? A : (3.14159265359f - A);
    float th  = phi * THIRD;                              // [0, pi/3]

    // cos(th), cos(th±2pi/3) via identity (th in [0,pi/3] => sin >= 0)
    float c0  = __cosf(th);
    float s0  = sqrtf(fmaxf(fmaf(-c0, c0, 1.0f), 0.0f));
    float cm  = -0.5f * c0;
    float c1  = fmaf(-0.86602540378f, s0, cm);            // -> min
    float c2c = fmaf( 0.86602540378f, s0, cm);            // -> mid
    float tsp = 2.0f * sp;
    float L1 = fmaf(tsp, c0,  m);                         // max
    float L2 = fmaf(tsp, c2c, m);                         // mid
    float L3 = fmaf(tsp, c1,  m);                         // min

    float g1 = __logf(L1), g2 = __logf(L2), g3 = __logf(L3);

    // stable divided differences (L1 >= L2 >= L3 > 0)
    float d12 = L1 - L2, d23 = L2 - L3;
    float d13 = fmaxf(L1 - L3, 1e-6f);
    float i2  = rcpf(L2), i3 = rcpf(L3);
    float x12 = d12 * i2, x23 = d23 * i3;
    // log1p(x)/x series, err <= x^4/5 (used only for x < 0.03)
    float s12 = fmaf(x12, fmaf(x12, fmaf(x12, -0.25f, THIRD), -0.5f), 1.0f);
    float s23 = fmaf(x23, fmaf(x23, fmaf(x23, -0.25f, THIRD), -0.5f), 1.0f);
    float f12 = (x12 < 0.03f) ? s12 * i2 : (g1 - g2) * rcpf(fmaxf(d12, 1e-30f));
    float f23 = (x23 < 0.03f) ? s23 * i3 : (g2 - g3) * rcpf(fmaxf(d23, 1e-30f));
    float cc2 = (f12 - f23) * rcpf(d13);

    float k0 = fmaf(cc2, L1 * L2, fmaf(-f12, L1, g1));
    float k1 = fmaf(-cc2, L1 + L2, f12);

    // M^2 (symmetric)
    float s00  = fmaf(a00, a00, fmaf(a01, a01, a02 * a02));
    float s11  = fmaf(a01, a01, fmaf(a11, a11, a12 * a12));
    float s22  = fmaf(a02, a02, fmaf(a12, a12, a22 * a22));
    float s01  = fmaf(a01, a00 + a11, a02 * a12);
    float s02  = fmaf(a02, a00 + a22, a01 * a12);
    float s12m = fmaf(a12, a11 + a22, a01 * a02);

    y00 = fmaf(cc2, s00,  fmaf(k1, a00, k0));
    y11 = fmaf(cc2, s11,  fmaf(k1, a11, k0));
    y22 = fmaf(cc2, s22,  fmaf(k1, a22, k0));
    y01 = fmaf(cc2, s01,  k1 * a01);
    y02 = fmaf(cc2, s02,  k1 * a02);
    y12 = fmaf(cc2, s12m, k1 * a12);
}

extern "C" __global__ void __launch_bounds__(256, 4)
logm_kernel(const float* __restrict__ x, float* __restrict__ y)
{
    int t = blockIdx.x * blockDim.x + threadIdx.x;     // < 524288
    int g = t << 2;                                    // first of 4 voxels
    int b = g >> 20;
    int v = g & (NV - 1);
    const float* xb = x + ((size_t)b * 9) * NV + v;
    float*       yb = y + ((size_t)b * 9) * NV + v;

    // upper-triangle planes only: c = 0,1,2,4,5,8
    float4 A00 = *reinterpret_cast<const float4*>(xb + 0 * (size_t)NV);
    float4 A01 = *reinterpret_cast<const float4*>(xb + 1 * (size_t)NV);
    float4 A02 = *reinterpret_cast<const float4*>(xb + 2 * (size_t)NV);
    float4 A11 = *reinterpret_cast<const float4*>(xb + 4 * (size_t)NV);
    float4 A12 = *reinterpret_cast<const float4*>(xb + 5 * (size_t)NV);
    float4 A22 = *reinterpret_cast<const float4*>(xb + 8 * (size_t)NV);

    float a00[4] = {A00.x, A00.y, A00.z, A00.w};
    float a01[4] = {A01.x, A01.y, A01.z, A01.w};
    float a02[4] = {A02.x, A02.y, A02.z, A02.w};
    float a11[4] = {A11.x, A11.y, A11.z, A11.w};
    float a12[4] = {A12.x, A12.y, A12.z, A12.w};
    float a22[4] = {A22.x, A22.y, A22.z, A22.w};

    float O00[4], O01[4], O02[4], O11[4], O12[4], O22[4];
#pragma unroll
    for (int j = 0; j < 4; ++j)
        logm3(a00[j], a01[j], a02[j], a11[j], a12[j], a22[j],
              O00[j], O01[j], O02[j], O11[j], O12[j], O22[j]);

    float4 W;
#define STORE(ch, arr) \
    W.x = arr[0]; W.y = arr[1]; W.z = arr[2]; W.w = arr[3]; \
    *reinterpret_cast<float4*>(yb + (size_t)(ch) * NV) = W;

    STORE(0, O00) STORE(1, O01) STORE(2, O02)
    STORE(3, O01) STORE(4, O11) STORE(5, O12)
    STORE(6, O02) STORE(7, O12) STORE(8, O22)
#undef STORE
}

extern "C" void kernel_launch(void* const* d_in, const int* in_sizes, int n_in,
                              void* d_out, int out_size, void* d_ws, size_t ws_size,
                              hipStream_t stream) {
    const float* x = (const float*)d_in[0];
    float*       y = (float*)d_out;
    const int total_threads = BT * NV / 4;             // 524288
    dim3 grid(total_threads / 256), block(256);
    hipLaunchKernelGGL(logm_kernel, grid, block, 0, stream, x, y);
}